// Round 13
// baseline (50.983 us; speedup 1.0000x reference)
//
#include <hip/hip_runtime.h>
#include <hip/hip_bf16.h>

#define EPS 1e-07f

#define BLOCK 1024
#define RPB   32            // rays per block (one wave-half per K-chunk)
#define NW    (BLOCK/64)    // 16 waves
#define REPS  4             // DIAGNOSTIC: repeat phase-2 4x, scale by 1/4

// sqrt(0.5*log2(e)) ; log2(sqrt(2*pi))
#define SQRT_HALF_LOG2E 0.84932180028801904f
#define LOG2_SQRT_2PI   1.32574806473616588f

typedef float v4f __attribute__((ext_vector_type(4)));

// ---------------------------------------------------------------------------
// DIAGNOSTIC build of the round-8 fused kernel: phase-2 executed REPS times
// (identical work; accumulator scaled by 1/REPS at the end; asm keep-alive
// blocks CSE across reps). Purpose: push kernel duration above the harness's
// ~38 us poison fills so rocprof's top-5 finally shows OUR counters
// (VALUBusy / Occupancy / VGPR / LDS conflicts), and decompose:
//   phase2_time = (dur13 - dur8) / (REPS-1)
// ---------------------------------------------------------------------------
__global__ __launch_bounds__(BLOCK) void fused_splat(
        const float* __restrict__ pos_raw,
        const float* __restrict__ conc_raw,
        const float* __restrict__ scale_raw,
        const float* __restrict__ rot_raw,
        const void*  __restrict__ map_size_p,
        const float* __restrict__ p_rays,
        const float* __restrict__ u_rays,
        float* __restrict__ out,
        int K, int R)
{
    // K/2 = 2048 Gaussians per pass -> 512 groups -> 48 KB
    __shared__ float sG[512][6][4];
    __shared__ float psum[NW][RPB];

    const int tid  = threadIdx.x;
    const int lane = tid & 63;
    const int wv   = tid >> 6;          // 0..15
    const int rayl = lane & 31;         // ray within block
    const int half = lane >> 5;         // 0/1
    const int chunk = (wv << 1) | half; // 0..31

    int ray = blockIdx.x * RPB + rayl;
    if (ray >= R) ray = R - 1;          // defensive (R % RPB == 0 normally)

    // map_size may arrive as int32 or float32 single-element array.
    unsigned int msbits = *(const unsigned int*)map_size_p;
    float msf = __uint_as_float(msbits);
    const float ms = (msf >= 1e-3f && msf <= 1e9f) ? msf
                                                   : (float)(*(const int*)map_size_p);

    // Per-ray coefficients.
    float2 p2 = *(const float2*)(p_rays + 2*ray);
    float2 u2 = *(const float2*)(u_rays + 2*ray);
    const float p0 = p2.x, p1 = p2.y, u0 = u2.x, u1 = u2.y;
    const float qu0  = u0*u0, qu1 = 2.0f*u0*u1, qu2 = u1*u1;
    const float wt   =  SQRT_HALF_LOG2E * (u0*p1 - u1*p0);
    const float su1  =  SQRT_HALF_LOG2E * u1;
    const float nsu0 = -SQRT_HALF_LOG2E * u0;

    float acc = 0.0f;

    const int KH = K >> 1;              // Gaussians per pass (2048)
    const int CL = KH >> 5;             // chunk length (64)
    const int NG = CL >> 2;             // groups per chunk (16)

    for (int pass = 0; pass < 2; ++pass) {
        const int kbase = pass * KH;

        __syncthreads();                // previous pass fully consumed

        // ---- phase 1: precompute this pass's Gaussians into LDS ----
        for (int k = tid; k < KH; k += BLOCK) {
            const int kg = kbase + k;

            float pr0 = pos_raw[2*kg], pr1 = pos_raw[2*kg+1];
            float pos0 = ms / (1.0f + __expf(-pr0));
            float pos1 = ms / (1.0f + __expf(-pr1));

            float cr = conc_raw[kg];
            float conc = fmaxf(cr, 0.0f) + __logf(1.0f + __expf(-fabsf(cr)));

            float s0 = __expf(scale_raw[2*kg]);
            float s1 = __expf(scale_raw[2*kg+1]);
            float d0 = 1.0f / (s0*s0 + EPS);
            float d1 = 1.0f / (s1*s1 + EPS);

            float rot = rot_raw[kg];
            float c = __cosf(rot), s = __sinf(rot);

            float m00 = c*c*d0 + s*s*d1;
            float m01 = c*s*(d0 - d1);
            float m11 = s*s*d0 + c*c*d1;

            float det    = d0 * d1;
            float invdet = 1.0f / det;
            float cc = __log2f(conc) + LOG2_SQRT_2PI - 0.5f * __log2f(det);

            const int q = k >> 2, e = k & 3;
            sG[q][0][e] = m00 * invdet;
            sG[q][1][e] = m01 * invdet;
            sG[q][2][e] = m11 * invdet;
            sG[q][3][e] = cc;
            sG[q][4][e] = pos0;
            sG[q][5][e] = pos1;
        }
        __syncthreads();

        // ---- phase 2: walk this wave-half's chunk, REPS times ----
        const int g0 = chunk * NG;
        #pragma unroll 1
        for (int rep = 0; rep < REPS; ++rep) {
            asm volatile("" : "+v"(acc));       // block CSE across reps
            #pragma unroll 4
            for (int gq = 0; gq < NG; ++gq) {
                const int t4 = g0 + gq;
                v4f M00 = *(const v4f*)&sG[t4][0][0];
                v4f M01 = *(const v4f*)&sG[t4][1][0];
                v4f M11 = *(const v4f*)&sG[t4][2][0];
                v4f CC  = *(const v4f*)&sG[t4][3][0];
                v4f P0  = *(const v4f*)&sG[t4][4][0];
                v4f P1  = *(const v4f*)&sG[t4][5][0];

                #pragma unroll
                for (int g = 0; g < 4; ++g) {
                    float a_  = fmaf(qu2, M11[g], fmaf(qu1, M01[g], qu0 * M00[g]));
                    float cr_ = fmaf(nsu0, P1[g], fmaf(su1, P0[g], wt));
                    float ra_ = __builtin_amdgcn_rsqf(a_);
                    float t_  = cr_ * ra_;
                    float ar_ = fmaf(-t_, t_, CC[g]);
                    float e_  = __builtin_amdgcn_exp2f(ar_);
                    acc = fmaf(ra_, e_, acc);
                }
            }
        }
    }

    acc *= (1.0f / REPS);

    // ---- reduction: 32 partials per ray -> one value ----
    acc += __shfl_xor(acc, 32, 64);          // merge the two halves
    if (half == 0) psum[wv][rayl] = acc;
    __syncthreads();

    if (wv == 0 && lane < RPB) {
        float s = 0.0f;
        #pragma unroll
        for (int w = 0; w < NW; ++w) s += psum[w][lane];
        int oray = blockIdx.x * RPB + lane;
        if (oray < R) out[oray] = s;
    }
}

// ---------------------------------------------------------------------------
extern "C" void kernel_launch(void* const* d_in, const int* in_sizes, int n_in,
                              void* d_out, int out_size, void* d_ws, size_t ws_size,
                              hipStream_t stream)
{
    const float* pos_raw   = (const float*)d_in[0];
    const float* conc_raw  = (const float*)d_in[1];
    const float* scale_raw = (const float*)d_in[2];
    const float* rot_raw   = (const float*)d_in[3];
    const float* p_rays    = (const float*)d_in[4];
    const float* u_rays    = (const float*)d_in[5];
    const void*  map_size  = d_in[6];

    const int K = in_sizes[1];          // conc_raw is (K,)
    const int R = out_size;             // output is (R,)

    float* out = (float*)d_out;

    dim3 grid((R + RPB - 1) / RPB);     // 256 blocks for R=8192
    fused_splat<<<grid, BLOCK, 0, stream>>>(pos_raw, conc_raw, scale_raw,
                                            rot_raw, map_size,
                                            p_rays, u_rays, out, K, R);
}

// Round 15
// 21.652 us; speedup vs baseline: 2.3547x; 2.3547x over previous
//
#include <hip/hip_runtime.h>
#include <hip/hip_bf16.h>

#define EPS 1e-07f

#define BLOCK   512         // splat block (8 waves)
#define RPB     32          // rays per block
#define SLICE_G 1024        // Gaussians per K-slice
#define NGRP    (SLICE_G/4) // 256 groups per slice
#define NW      (BLOCK/64)  // 8 waves
#define PBLOCK  64          // precompute block size

// sqrt(0.5*log2(e)) ; log2(sqrt(2*pi))
#define SQRT_HALF_LOG2E 0.84932180028801904f
#define LOG2_SQRT_2PI   1.32574806473616588f

typedef float v4f __attribute__((ext_vector_type(4)));

// ---------------------------------------------------------------------------
// Kernel 1: one-shot per-Gaussian precompute + zero d_out.
// Cross-product identity: c0 - b^2/a = (u x (p-pos))^2 / a',  a' = u^T(S/detS)u
// Group-interleaved table gG[group][24]:
//   [0..3]=m00' [4..7]=m01' [8..11]=m11' [12..15]=cc [16..19]=pos0 [20..23]=pos1
// Pad records (k >= K): cc = -1e38 -> exp2 -> exactly 0 contribution.
// ---------------------------------------------------------------------------
__global__ __launch_bounds__(PBLOCK) void precompute_gauss(
                                 const float* __restrict__ pos_raw,
                                 const float* __restrict__ conc_raw,
                                 const float* __restrict__ scale_raw,
                                 const float* __restrict__ rot_raw,
                                 const void*  __restrict__ map_size_p,
                                 float* __restrict__ gG,
                                 float* __restrict__ out,
                                 int K, int KPAD, int R)
{
    int k = blockIdx.x * blockDim.x + threadIdx.x;
    int nthreads = gridDim.x * blockDim.x;

    // Zero the output (ordered before splat_main on the same stream).
    for (int i = k; i < R; i += nthreads) out[i] = 0.0f;

    if (k >= KPAD) return;

    const int q = k >> 2, e = k & 3;
    float* rec = gG + q * 24;

    if (k >= K) {               // pad: contributes exactly 0
        rec[0  + e] = 1.0f;
        rec[4  + e] = 0.0f;
        rec[8  + e] = 1.0f;
        rec[12 + e] = -1e38f;
        rec[16 + e] = 0.0f;
        rec[20 + e] = 0.0f;
        return;
    }

    // map_size may arrive as int32 or float32 single-element array.
    unsigned int msbits = *(const unsigned int*)map_size_p;
    float msf = __uint_as_float(msbits);
    const float ms = (msf >= 1e-3f && msf <= 1e9f) ? msf
                                                   : (float)(*(const int*)map_size_p);

    float pr0 = pos_raw[2*k],  pr1 = pos_raw[2*k+1];
    float pos0 = ms / (1.0f + __expf(-pr0));   // sigmoid * map_size
    float pos1 = ms / (1.0f + __expf(-pr1));

    float cr = conc_raw[k];
    float conc = fmaxf(cr, 0.0f) + __logf(1.0f + __expf(-fabsf(cr)));  // softplus

    float s0 = __expf(scale_raw[2*k]);
    float s1 = __expf(scale_raw[2*k+1]);
    float d0 = 1.0f / (s0*s0 + EPS);
    float d1 = 1.0f / (s1*s1 + EPS);

    float rot = rot_raw[k];
    float c = __cosf(rot), s = __sinf(rot);

    float m00 = c*c*d0 + s*s*d1;
    float m01 = c*s*(d0 - d1);
    float m11 = s*s*d0 + c*c*d1;

    float det    = d0 * d1;
    float invdet = 1.0f / det;
    float cc = __log2f(conc) + LOG2_SQRT_2PI - 0.5f * __log2f(det);

    rec[0  + e] = m00 * invdet;
    rec[4  + e] = m01 * invdet;
    rec[8  + e] = m11 * invdet;
    rec[12 + e] = cc;
    rec[16 + e] = pos0;
    rec[20 + e] = pos1;
}

// ---------------------------------------------------------------------------
// Kernel 2: splat. grid = (R/32 ray-groups) x (KPAD/1024 K-slices),
// 512 threads = 8 waves; 4 blocks/CU (2048 thr, 96KB LDS) so staging,
// barriers and tails of one block hide under another's compute.
// Each block: stage its slice's 256-group table (24 KB = NGRP*24 floats)
// from gG via float4 copy, then wave-half (wv,half) walks its chunk of 64
// Gaussians (16 groups); all 32 lanes of a half read the same address
// (broadcast, 2 addr/wave = free).
// Inner loop identical to R8 (measured at ~100% issue roofline:
// 32 VALU*2 + 8 trans*16 = 192 cyc / 256 pairs).
// Reduction: shfl_xor(32) + LDS tree + one atomicAdd per (ray, slice).
// ---------------------------------------------------------------------------
__global__ __launch_bounds__(BLOCK) void splat_main(
        const float* __restrict__ p_rays,
        const float* __restrict__ u_rays,
        const float* __restrict__ gG,
        float* __restrict__ out,
        int R)
{
    __shared__ v4f  sG4[NGRP * 6];      // 24 KB
    __shared__ float psum[NW][RPB];

    const int tid   = threadIdx.x;
    const int lane  = tid & 63;
    const int wv    = tid >> 6;         // 0..7
    const int rayl  = lane & 31;
    const int half  = lane >> 5;        // 0/1
    const int chunk = (wv << 1) | half; // 0..15
    const int NG    = NGRP / 16;        // 16 groups per chunk

    int ray = blockIdx.x * RPB + rayl;
    if (ray >= R) ray = R - 1;

    // ---- stage this slice from global (linear float4 copy) ----
    // Per-slice footprint is NGRP*24 floats (24 KB), NOT SLICE_G*24.
    {
        const v4f* src = (const v4f*)(gG + (size_t)blockIdx.y * NGRP * 24);
        #pragma unroll
        for (int i = 0; i < (NGRP * 6) / BLOCK; ++i)
            sG4[tid + i * BLOCK] = src[tid + i * BLOCK];
    }

    // Per-ray coefficients (overlaps staging latency).
    float2 p2 = *(const float2*)(p_rays + 2*ray);
    float2 u2 = *(const float2*)(u_rays + 2*ray);
    const float p0 = p2.x, p1 = p2.y, u0 = u2.x, u1 = u2.y;
    const float qu0  = u0*u0, qu1 = 2.0f*u0*u1, qu2 = u1*u1;
    const float wt   =  SQRT_HALF_LOG2E * (u0*p1 - u1*p0);
    const float su1  =  SQRT_HALF_LOG2E * u1;
    const float nsu0 = -SQRT_HALF_LOG2E * u0;

    __syncthreads();

    // ---- walk this wave-half's chunk ----
    float acc = 0.0f;
    const int g0 = chunk * NG;
    #pragma unroll 4
    for (int gq = 0; gq < NG; ++gq) {
        const v4f* g = &sG4[(g0 + gq) * 6];
        v4f M00 = g[0];
        v4f M01 = g[1];
        v4f M11 = g[2];
        v4f CC  = g[3];
        v4f P0  = g[4];
        v4f P1  = g[5];

        #pragma unroll
        for (int e = 0; e < 4; ++e) {
            float a_  = fmaf(qu2, M11[e], fmaf(qu1, M01[e], qu0 * M00[e]));
            float cr_ = fmaf(nsu0, P1[e], fmaf(su1, P0[e], wt));
            float ra_ = __builtin_amdgcn_rsqf(a_);
            float t_  = cr_ * ra_;
            float ar_ = fmaf(-t_, t_, CC[e]);
            float e_  = __builtin_amdgcn_exp2f(ar_);
            acc = fmaf(ra_, e_, acc);
        }
    }

    // ---- reduction: 16 chunk-partials per ray -> one atomic ----
    acc += __shfl_xor(acc, 32, 64);          // merge the two halves
    if (half == 0) psum[wv][rayl] = acc;
    __syncthreads();

    if (wv == 0 && lane < RPB) {
        float s = 0.0f;
        #pragma unroll
        for (int w = 0; w < NW; ++w) s += psum[w][lane];
        int oray = blockIdx.x * RPB + lane;
        if (oray < R) atomicAdd(&out[oray], s);
    }
}

// ---------------------------------------------------------------------------
extern "C" void kernel_launch(void* const* d_in, const int* in_sizes, int n_in,
                              void* d_out, int out_size, void* d_ws, size_t ws_size,
                              hipStream_t stream)
{
    const float* pos_raw   = (const float*)d_in[0];
    const float* conc_raw  = (const float*)d_in[1];
    const float* scale_raw = (const float*)d_in[2];
    const float* rot_raw   = (const float*)d_in[3];
    const float* p_rays    = (const float*)d_in[4];
    const float* u_rays    = (const float*)d_in[5];
    const void*  map_size  = d_in[6];

    const int K = in_sizes[1];          // conc_raw is (K,)
    const int R = out_size;             // output is (R,)

    const int NSLICE = (K + SLICE_G - 1) / SLICE_G;   // 4 for K=4096
    const int KPAD   = NSLICE * SLICE_G;

    float* out = (float*)d_out;
    float* gG  = (float*)d_ws;          // (KPAD/4) * 24 floats

    {
        dim3 grid((KPAD + PBLOCK - 1) / PBLOCK);
        precompute_gauss<<<grid, PBLOCK, 0, stream>>>(pos_raw, conc_raw, scale_raw,
                                                      rot_raw, map_size,
                                                      gG, out, K, KPAD, R);
    }
    {
        dim3 grid((R + RPB - 1) / RPB, NSLICE);       // 256 x 4 = 1024 blocks
        splat_main<<<grid, BLOCK, 0, stream>>>(p_rays, u_rays, gG, out, R);
    }
}